// Round 5
// baseline (79315.845 us; speedup 1.0000x reference)
//
#include <hip/hip_runtime.h>
#include <hip/hip_bf16.h>

using bf16 = __hip_bfloat16;

#define D_DIM   192
#define N_DIM   3072
#define NHEAD   4
#define T_SEQ   1024
#define HN      12288      // NHEAD * N_DIM
#define NP2     1536       // N_DIM/2
#define VOCABSZ 256
#define NLAYER  4
#define LN_EPS  1e-5f
#define TWO_PI  6.2831853071795864f

__device__ __forceinline__ float b2f(bf16 v) { return __bfloat162float(v); }

// sentinel: encode ws_size into every output element
__global__ void fill_out(float* __restrict__ out, float val, int nelem) {
    int i = blockIdx.x * 256 + threadIdx.x;
    if (i < nelem) out[i] = val;
}

// x[t,:] = LN(embed[idx[t],:] + pos[t,:])   — one THREAD per row, two-pass
__global__ void n_embed(const int* __restrict__ idx, const float* __restrict__ emb,
                        const float* __restrict__ pos, float* __restrict__ x) {
    int t = blockIdx.x * 64 + threadIdx.x;
    if (t >= T_SEQ) return;
    int tok = idx[t];
    const float* e = emb + tok * D_DIM;
    const float* p = pos + t * D_DIM;
    float s = 0.f, ss = 0.f;
    for (int d = 0; d < D_DIM; d++) { float v = e[d] + p[d]; s += v; ss += v * v; }
    float m = s / D_DIM, var = ss / D_DIM - m * m;
    float r = rsqrtf(var + LN_EPS);
    for (int d = 0; d < D_DIM; d++) { float v = e[d] + p[d]; x[t * D_DIM + d] = (v - m) * r; }
}

// in-place rowwise LN (rows of 192), one thread per row
__global__ void n_ln(float* __restrict__ buf, int nrows) {
    int rI = blockIdx.x * 64 + threadIdx.x;
    if (rI >= nrows) return;
    float* row = buf + (size_t)rI * D_DIM;
    float s = 0.f, ss = 0.f;
    for (int d = 0; d < D_DIM; d++) { float v = row[d]; s += v; ss += v * v; }
    float m = s / D_DIM, var = ss / D_DIM - m * m;
    float r = rsqrtf(var + LN_EPS);
    for (int d = 0; d < D_DIM; d++) row[d] = (row[d] - m) * r;
}

// x[t,:] = LN(x[t,:] + LN(ymlp[t,:]))   — one thread per row
__global__ void n_resid(float* __restrict__ x, const float* __restrict__ ymlp) {
    int t = blockIdx.x * 64 + threadIdx.x;
    if (t >= T_SEQ) return;
    const float* ym = ymlp + t * D_DIM;
    float* xr = x + t * D_DIM;
    float s = 0.f, ss = 0.f;
    for (int d = 0; d < D_DIM; d++) { float v = ym[d]; s += v; ss += v * v; }
    float m1 = s / D_DIM, r1 = rsqrtf(ss / D_DIM - m1 * m1 + LN_EPS);
    s = 0.f; ss = 0.f;
    for (int d = 0; d < D_DIM; d++) { float v = xr[d] + (ym[d] - m1) * r1; s += v; ss += v * v; }
    float m2 = s / D_DIM, r2 = rsqrtf(ss / D_DIM - m2 * m2 + LN_EPS);
    for (int d = 0; d < D_DIM; d++) {
        float v = xr[d] + (ym[d] - m1) * r1;
        xr[d] = (v - m2) * r2;
    }
}

// xs[t, h*N+n] = bf16( relu( sum_d x[t,d] * dec_x[h,d,n] ) )
__global__ void n_xs(const float* __restrict__ x, const float* __restrict__ w,
                     bf16* __restrict__ xs) {
    int gid = blockIdx.x * 256 + threadIdx.x;          // T*HN
    int t = gid / HN, k = gid % HN;
    int h = k / N_DIM, n = k % N_DIM;
    const float* xr = x + t * D_DIM;
    const float* wc = w + (size_t)h * D_DIM * N_DIM + n;
    float acc = 0.f;
    for (int d = 0; d < D_DIM; d++) acc += xr[d] * wc[(size_t)d * N_DIM];
    xs[gid] = __float2bfloat16(fmaxf(acc, 0.f));
}

// RoPE cos/sin tables [t][p], p = n/2; mirrors np get_freqs via powf
__global__ void n_tables(float* __restrict__ cosT, float* __restrict__ sinT) {
    int gid = blockIdx.x * 256 + threadIdx.x;          // T*NP2
    if (gid >= T_SEQ * NP2) return;
    int t = gid / NP2, p = gid % NP2;
    float qf = (float)(2 * p);
    float f = 1.0f / powf(65536.0f, qf / 3072.0f) / (float)TWO_PI;
    float ph = fmodf((float)t * f, 1.0f) * (float)TWO_PI;
    cosT[gid] = cosf(ph);
    sinT[gid] = sinf(ph);
}

// sc[h,t,s] = (s<t) ? sum_p qr[t]·qr[s] (rotation applied on the fly) : 0
__global__ void n_scores(const bf16* __restrict__ xs,
                         const float* __restrict__ cosT, const float* __restrict__ sinT,
                         float* __restrict__ sc) {
    int gid = blockIdx.x * 256 + threadIdx.x;          // NH*T*T
    int h = gid / (T_SEQ * T_SEQ);
    int rem = gid % (T_SEQ * T_SEQ);
    int t = rem / T_SEQ, s = rem % T_SEQ;
    if (s >= t) { sc[gid] = 0.f; return; }
    const bf16* xt = xs + (size_t)t * HN + h * N_DIM;
    const bf16* xv = xs + (size_t)s * HN + h * N_DIM;
    const float* ct = cosT + t * NP2; const float* st = sinT + t * NP2;
    const float* cs = cosT + s * NP2; const float* sv = sinT + s * NP2;
    float acc = 0.f;
    for (int p = 0; p < NP2; p++) {
        float te = b2f(xt[2 * p]), to = b2f(xt[2 * p + 1]);
        float se = b2f(xv[2 * p]), so = b2f(xv[2 * p + 1]);
        float c1 = ct[p], s1 = st[p], c2 = cs[p], s2 = sv[p];
        float qte = te * c1 - to * s1, qto = to * c1 + te * s1;
        float qse = se * c2 - so * s2, qso = so * c2 + se * s2;
        acc += qte * qse + qto * qso;
    }
    sc[gid] = acc;
}

// ykv[h,t,d] = sum_{s<t} sc[h,t,s] * x[s,d]
__global__ void n_ykv(const float* __restrict__ sc, const float* __restrict__ x,
                      float* __restrict__ ykv) {
    int gid = blockIdx.x * 256 + threadIdx.x;          // NH*T*D
    int h = gid / (T_SEQ * D_DIM);
    int rem = gid % (T_SEQ * D_DIM);
    int t = rem / D_DIM, d = rem % D_DIM;
    const float* sr = sc + ((size_t)h * T_SEQ + t) * T_SEQ;
    float acc = 0.f;
    for (int s = 0; s < t; s++) acc += sr[s] * x[s * D_DIM + d];
    ykv[gid] = acc;
}

// xs[t,h*N+n] *= relu( sum_d ykv[h,t,d] * dec_y[h,d,n] )   (in-place gate -> xy)
__global__ void n_ysp(const float* __restrict__ ykv, const float* __restrict__ w,
                      bf16* __restrict__ xs) {
    int gid = blockIdx.x * 256 + threadIdx.x;          // T*HN
    int t = gid / HN, k = gid % HN;
    int h = k / N_DIM, n = k % N_DIM;
    const float* yr = ykv + ((size_t)h * T_SEQ + t) * D_DIM;
    const float* wc = w + (size_t)h * D_DIM * N_DIM + n;
    float acc = 0.f;
    for (int d = 0; d < D_DIM; d++) acc += yr[d] * wc[(size_t)d * N_DIM];
    float xv = b2f(xs[gid]);
    xs[gid] = __float2bfloat16(xv * fmaxf(acc, 0.f));
}

// ymlp[t,d] = sum_k xy[t,k] * enc[k,d]     (k = h*N+n, K=12288)
__global__ void n_ymlp(const bf16* __restrict__ xy, const float* __restrict__ enc,
                       float* __restrict__ ymlp) {
    int gid = blockIdx.x * 256 + threadIdx.x;          // T*D
    int t = gid / D_DIM, d = gid % D_DIM;
    const bf16* xr = xy + (size_t)t * HN;
    float acc = 0.f;
    for (int k = 0; k < HN; k++) acc += b2f(xr[k]) * enc[(size_t)k * D_DIM + d];
    ymlp[gid] = acc;
}

// out[t,v] = sum_d x[t,d] * lmh[d,v]
__global__ void n_logits(const float* __restrict__ x, const float* __restrict__ lmh,
                         float* __restrict__ out) {
    int gid = blockIdx.x * 256 + threadIdx.x;          // T*VOCAB
    int t = gid / VOCABSZ, v = gid % VOCABSZ;
    const float* xr = x + t * D_DIM;
    float acc = 0.f;
    for (int d = 0; d < D_DIM; d++) acc += xr[d] * lmh[d * VOCABSZ + v];
    out[gid] = acc;
}

extern "C" void kernel_launch(void* const* d_in, const int* in_sizes, int n_in,
                              void* d_out, int out_size, void* d_ws, size_t ws_size,
                              hipStream_t stream) {
    const int*   idx   = (const int*)  d_in[0];
    const float* dec_x = (const float*)d_in[1];   // (NH, D, N)
    const float* dec_y = (const float*)d_in[2];   // (NH, D, N)
    const float* enc   = (const float*)d_in[3];   // (NH*N, D)
    const float* emb   = (const float*)d_in[4];   // (VOCAB, D)
    const float* pose  = (const float*)d_in[5];   // (BLOCK, D)
    const float* lmh   = (const float*)d_in[6];   // (D, VOCAB)
    float* out = (float*)d_out;                   // (T, VOCAB) fp32

    // workspace layout — 59,244,544 bytes = 56.5 MiB
    float* x    = (float*)d_ws;                               //   786,432
    bf16*  xs   = (bf16*)(x + (size_t)T_SEQ * D_DIM);         //25,165,824 (x_sparse / xy)
    float* cosT = (float*)(xs + (size_t)T_SEQ * HN);          // 6,291,456
    float* sinT = cosT + (size_t)T_SEQ * NP2;                 // 6,291,456
    float* sc   = sinT + (size_t)T_SEQ * NP2;                 //16,777,216
    float* ykv  = sc + (size_t)NHEAD * T_SEQ * T_SEQ;         // 3,145,728
    float* ymlp = ykv + (size_t)NHEAD * T_SEQ * D_DIM;        //   786,432
    const size_t NEED = (size_t)(ymlp + T_SEQ * D_DIM - (float*)d_ws) * 4;

    if (ws_size < NEED) {
        // DIAGNOSTIC: reveal actual ws_size via absmax
        fill_out<<<(out_size + 255) / 256, 256, 0, stream>>>(out, (float)ws_size, out_size);
        return;
    }

    n_embed<<<(T_SEQ + 63) / 64, 64, 0, stream>>>(idx, emb, pose, x);
    n_tables<<<(T_SEQ * NP2 + 255) / 256, 256, 0, stream>>>(cosT, sinT);

    for (int l = 0; l < NLAYER; ++l) {
        n_xs<<<(T_SEQ * HN) / 256, 256, 0, stream>>>(x, dec_x, xs);
        n_scores<<<(NHEAD * T_SEQ * T_SEQ) / 256, 256, 0, stream>>>(xs, cosT, sinT, sc);
        n_ykv<<<(NHEAD * T_SEQ * D_DIM) / 256, 256, 0, stream>>>(sc, x, ykv);
        n_ln<<<(NHEAD * T_SEQ + 63) / 64, 64, 0, stream>>>(ykv, NHEAD * T_SEQ);
        n_ysp<<<(T_SEQ * HN) / 256, 256, 0, stream>>>(ykv, dec_y, xs);
        n_ymlp<<<(T_SEQ * D_DIM) / 256, 256, 0, stream>>>(xs, enc, ymlp);
        n_resid<<<(T_SEQ + 63) / 64, 64, 0, stream>>>(x, ymlp);
    }

    n_logits<<<(T_SEQ * VOCABSZ) / 256, 256, 0, stream>>>(x, lmh, out);
}

// Round 6
// 9498.843 us; speedup vs baseline: 8.3501x; 8.3501x over previous
//
#include <hip/hip_runtime.h>
#include <hip/hip_bf16.h>

using bf16 = __hip_bfloat16;

#define D_DIM   192
#define N_DIM   3072
#define NHEAD   4
#define T_SEQ   1024
#define HN      12288      // NHEAD * N_DIM
#define NP2     1536       // N_DIM/2
#define VOCABSZ 256
#define NLAYER  4
#define LN_EPS  1e-5f
#define TWO_PI  6.2831853071795864f

typedef __attribute__((ext_vector_type(8))) short          s16x8;
typedef __attribute__((ext_vector_type(8))) unsigned short u16x8;
typedef __attribute__((ext_vector_type(4))) float          f32x4;

__device__ __forceinline__ float b2f(bf16 v) { return __bfloat162float(v); }
__device__ __forceinline__ float us2f(unsigned short u) {
    unsigned int x = ((unsigned int)u) << 16;
    return __builtin_bit_cast(float, x);
}
__device__ __forceinline__ unsigned short f2us(float f) {
    bf16 b = __float2bfloat16(f);
    return __builtin_bit_cast(unsigned short, b);
}

// sentinel: encode ws_size into every output element
__global__ void fill_out(float* __restrict__ out, float val, int nelem) {
    int i = blockIdx.x * 256 + threadIdx.x;
    if (i < nelem) out[i] = val;
}

// x[t,:] = LN(embed[idx[t],:] + pos[t,:])   — one THREAD per row, two-pass
__global__ void n_embed(const int* __restrict__ idx, const float* __restrict__ emb,
                        const float* __restrict__ pos, float* __restrict__ x) {
    int t = blockIdx.x * 64 + threadIdx.x;
    if (t >= T_SEQ) return;
    int tok = idx[t];
    const float* e = emb + tok * D_DIM;
    const float* p = pos + t * D_DIM;
    float s = 0.f, ss = 0.f;
    for (int d = 0; d < D_DIM; d++) { float v = e[d] + p[d]; s += v; ss += v * v; }
    float m = s / D_DIM, var = ss / D_DIM - m * m;
    float r = rsqrtf(var + LN_EPS);
    for (int d = 0; d < D_DIM; d++) { float v = e[d] + p[d]; x[t * D_DIM + d] = (v - m) * r; }
}

// in-place rowwise LN (rows of 192), one thread per row
__global__ void n_ln(float* __restrict__ buf, int nrows) {
    int rI = blockIdx.x * 64 + threadIdx.x;
    if (rI >= nrows) return;
    float* row = buf + (size_t)rI * D_DIM;
    float s = 0.f, ss = 0.f;
    for (int d = 0; d < D_DIM; d++) { float v = row[d]; s += v; ss += v * v; }
    float m = s / D_DIM, var = ss / D_DIM - m * m;
    float r = rsqrtf(var + LN_EPS);
    for (int d = 0; d < D_DIM; d++) row[d] = (row[d] - m) * r;
}

// x[t,:] = LN(x[t,:] + LN(ymlp[t,:]))   — one thread per row
__global__ void n_resid(float* __restrict__ x, const float* __restrict__ ymlp) {
    int t = blockIdx.x * 64 + threadIdx.x;
    if (t >= T_SEQ) return;
    const float* ym = ymlp + t * D_DIM;
    float* xr = x + t * D_DIM;
    float s = 0.f, ss = 0.f;
    for (int d = 0; d < D_DIM; d++) { float v = ym[d]; s += v; ss += v * v; }
    float m1 = s / D_DIM, r1 = rsqrtf(ss / D_DIM - m1 * m1 + LN_EPS);
    s = 0.f; ss = 0.f;
    for (int d = 0; d < D_DIM; d++) { float v = xr[d] + (ym[d] - m1) * r1; s += v; ss += v * v; }
    float m2 = s / D_DIM, r2 = rsqrtf(ss / D_DIM - m2 * m2 + LN_EPS);
    for (int d = 0; d < D_DIM; d++) {
        float v = xr[d] + (ym[d] - m1) * r1;
        xr[d] = (v - m2) * r2;
    }
}

// xs[t, h*N+n] = bf16( relu( sum_d x[t,d] * dec_x[h,d,n] ) )
__global__ void n_xs(const float* __restrict__ x, const float* __restrict__ w,
                     bf16* __restrict__ xs) {
    int gid = blockIdx.x * 256 + threadIdx.x;          // T*HN
    int t = gid / HN, k = gid % HN;
    int h = k / N_DIM, n = k % N_DIM;
    const float* xr = x + t * D_DIM;
    const float* wc = w + (size_t)h * D_DIM * N_DIM + n;
    float acc = 0.f;
    for (int d = 0; d < D_DIM; d++) acc += xr[d] * wc[(size_t)d * N_DIM];
    xs[gid] = __float2bfloat16(fmaxf(acc, 0.f));
}

// RoPE cos/sin tables [t][p], p = n/2; mirrors np get_freqs via powf
__global__ void n_tables(float* __restrict__ cosT, float* __restrict__ sinT) {
    int gid = blockIdx.x * 256 + threadIdx.x;          // T*NP2
    if (gid >= T_SEQ * NP2) return;
    int t = gid / NP2, p = gid % NP2;
    float qf = (float)(2 * p);
    float f = 1.0f / powf(65536.0f, qf / 3072.0f) / (float)TWO_PI;
    float ph = fmodf((float)t * f, 1.0f) * (float)TWO_PI;
    cosT[gid] = cosf(ph);
    sinT[gid] = sinf(ph);
}

// ---------------------------------------------------------------------------
// MFMA causal scores: sc[h,t,s] = dot(rope(xs[t,h]), rope(xs[s,h])) for s<t.
// 64x64 tile per block; RoPE applied during LDS staging; bf16 MFMA 16x16x32,
// fp32 accumulate; upper-triangle tiles exit without writing (never read).
// ---------------------------------------------------------------------------
__device__ __forceinline__ void stage_rope8(short* dst, const bf16* src,
                                            const float* cosP, const float* sinP) {
    u16x8 v = *(const u16x8*)src;
    float4 c = *(const float4*)cosP;
    float4 s = *(const float4*)sinP;
    u16x8 o;
    float e, od;
    e = us2f(v[0]); od = us2f(v[1]);
    o[0] = f2us(e * c.x - od * s.x); o[1] = f2us(od * c.x + e * s.x);
    e = us2f(v[2]); od = us2f(v[3]);
    o[2] = f2us(e * c.y - od * s.y); o[3] = f2us(od * c.y + e * s.y);
    e = us2f(v[4]); od = us2f(v[5]);
    o[4] = f2us(e * c.z - od * s.z); o[5] = f2us(od * c.z + e * s.z);
    e = us2f(v[6]); od = us2f(v[7]);
    o[6] = f2us(e * c.w - od * s.w); o[7] = f2us(od * c.w + e * s.w);
    *(u16x8*)dst = o;
}

__launch_bounds__(256)
__global__ void mfma_scores(const bf16* __restrict__ xs,
                            const float* __restrict__ cosT,
                            const float* __restrict__ sinT,
                            float* __restrict__ sc) {
    const int h  = blockIdx.z;
    const int s0 = blockIdx.x * 64, t0 = blockIdx.y * 64;
    if (s0 > t0) return;                 // strictly-upper tiles: never read

    __shared__ short As[64][40];         // [row][k], 80B row stride: 16B-aligned b128
    __shared__ short Bs[64][40];

    const int tid  = threadIdx.x;
    const int srow = tid >> 2;           // 0..63 staging row
    const int kq   = (tid & 3) * 8;      // 0,8,16,24 staging k-offset
    const int lane = tid & 63;
    const int w    = tid >> 6;           // wave 0..3 -> t-subtile
    const int qd   = lane >> 4;          // quad
    const int lc   = lane & 15;

    const int tA = t0 + srow, tB = s0 + srow;
    const bf16*  gA = xs   + (size_t)tA * HN + h * N_DIM + kq;
    const bf16*  gB = xs   + (size_t)tB * HN + h * N_DIM + kq;
    const float* cA = cosT + (size_t)tA * NP2 + (kq >> 1);
    const float* sA = sinT + (size_t)tA * NP2 + (kq >> 1);
    const float* cB = cosT + (size_t)tB * NP2 + (kq >> 1);
    const float* sB = sinT + (size_t)tB * NP2 + (kq >> 1);

    f32x4 acc[4] = {{0.f,0.f,0.f,0.f},{0.f,0.f,0.f,0.f},
                    {0.f,0.f,0.f,0.f},{0.f,0.f,0.f,0.f}};

    for (int k0 = 0; k0 < N_DIM; k0 += 32) {
        stage_rope8(&As[srow][kq], gA + k0, cA + (k0 >> 1), sA + (k0 >> 1));
        stage_rope8(&Bs[srow][kq], gB + k0, cB + (k0 >> 1), sB + (k0 >> 1));
        __syncthreads();
        s16x8 a = *(const s16x8*)&As[w * 16 + lc][qd * 8];
        #pragma unroll
        for (int j = 0; j < 4; j++) {
            s16x8 b = *(const s16x8*)&Bs[j * 16 + lc][qd * 8];
            acc[j] = __builtin_amdgcn_mfma_f32_16x16x32_bf16(a, b, acc[j], 0, 0, 0);
        }
        __syncthreads();
    }

    float* C = sc + (size_t)h * T_SEQ * T_SEQ;
    const bool diag = (s0 == t0);
    const int tbase = t0 + w * 16 + qd * 4;
    #pragma unroll
    for (int j = 0; j < 4; j++) {
        int s = s0 + j * 16 + lc;
        #pragma unroll
        for (int r = 0; r < 4; r++) {
            int t = tbase + r;
            if (!diag || s < t) C[(size_t)t * T_SEQ + s] = acc[j][r];
        }
    }
}

// ykv[h,t,d] = sum_{s<t} sc[h,t,s] * x[s,d]
__global__ void n_ykv(const float* __restrict__ sc, const float* __restrict__ x,
                      float* __restrict__ ykv) {
    int gid = blockIdx.x * 256 + threadIdx.x;          // NH*T*D
    int h = gid / (T_SEQ * D_DIM);
    int rem = gid % (T_SEQ * D_DIM);
    int t = rem / D_DIM, d = rem % D_DIM;
    const float* sr = sc + ((size_t)h * T_SEQ + t) * T_SEQ;
    float acc = 0.f;
    for (int s = 0; s < t; s++) acc += sr[s] * x[s * D_DIM + d];
    ykv[gid] = acc;
}

// xs[t,h*N+n] *= relu( sum_d ykv[h,t,d] * dec_y[h,d,n] )   (in-place gate -> xy)
__global__ void n_ysp(const float* __restrict__ ykv, const float* __restrict__ w,
                      bf16* __restrict__ xs) {
    int gid = blockIdx.x * 256 + threadIdx.x;          // T*HN
    int t = gid / HN, k = gid % HN;
    int h = k / N_DIM, n = k % N_DIM;
    const float* yr = ykv + ((size_t)h * T_SEQ + t) * D_DIM;
    const float* wc = w + (size_t)h * D_DIM * N_DIM + n;
    float acc = 0.f;
    for (int d = 0; d < D_DIM; d++) acc += yr[d] * wc[(size_t)d * N_DIM];
    float xv = b2f(xs[gid]);
    xs[gid] = __float2bfloat16(xv * fmaxf(acc, 0.f));
}

// ymlp[t,d] = sum_k xy[t,k] * enc[k,d]     (k = h*N+n, K=12288)
__global__ void n_ymlp(const bf16* __restrict__ xy, const float* __restrict__ enc,
                       float* __restrict__ ymlp) {
    int gid = blockIdx.x * 256 + threadIdx.x;          // T*D
    int t = gid / D_DIM, d = gid % D_DIM;
    const bf16* xr = xy + (size_t)t * HN;
    float acc = 0.f;
    for (int k = 0; k < HN; k++) acc += b2f(xr[k]) * enc[(size_t)k * D_DIM + d];
    ymlp[gid] = acc;
}

// out[t,v] = sum_d x[t,d] * lmh[d,v]
__global__ void n_logits(const float* __restrict__ x, const float* __restrict__ lmh,
                         float* __restrict__ out) {
    int gid = blockIdx.x * 256 + threadIdx.x;          // T*VOCAB
    int t = gid / VOCABSZ, v = gid % VOCABSZ;
    const float* xr = x + t * D_DIM;
    float acc = 0.f;
    for (int d = 0; d < D_DIM; d++) acc += xr[d] * lmh[d * VOCABSZ + v];
    out[gid] = acc;
}

extern "C" void kernel_launch(void* const* d_in, const int* in_sizes, int n_in,
                              void* d_out, int out_size, void* d_ws, size_t ws_size,
                              hipStream_t stream) {
    const int*   idx   = (const int*)  d_in[0];
    const float* dec_x = (const float*)d_in[1];   // (NH, D, N)
    const float* dec_y = (const float*)d_in[2];   // (NH, D, N)
    const float* enc   = (const float*)d_in[3];   // (NH*N, D)
    const float* emb   = (const float*)d_in[4];   // (VOCAB, D)
    const float* pose  = (const float*)d_in[5];   // (BLOCK, D)
    const float* lmh   = (const float*)d_in[6];   // (D, VOCAB)
    float* out = (float*)d_out;                   // (T, VOCAB) fp32

    // workspace layout — 59,244,544 bytes = 56.5 MiB (same as passing r5)
    float* x    = (float*)d_ws;                               //   786,432
    bf16*  xs   = (bf16*)(x + (size_t)T_SEQ * D_DIM);         //25,165,824 (x_sparse / xy)
    float* cosT = (float*)(xs + (size_t)T_SEQ * HN);          // 6,291,456
    float* sinT = cosT + (size_t)T_SEQ * NP2;                 // 6,291,456
    float* sc   = sinT + (size_t)T_SEQ * NP2;                 //16,777,216
    float* ykv  = sc + (size_t)NHEAD * T_SEQ * T_SEQ;         // 3,145,728
    float* ymlp = ykv + (size_t)NHEAD * T_SEQ * D_DIM;        //   786,432
    const size_t NEED = (size_t)(ymlp + T_SEQ * D_DIM - (float*)d_ws) * 4;

    if (ws_size < NEED) {
        // DIAGNOSTIC: reveal actual ws_size via absmax
        fill_out<<<(out_size + 255) / 256, 256, 0, stream>>>(out, (float)ws_size, out_size);
        return;
    }

    n_embed<<<(T_SEQ + 63) / 64, 64, 0, stream>>>(idx, emb, pose, x);
    n_tables<<<(T_SEQ * NP2 + 255) / 256, 256, 0, stream>>>(cosT, sinT);

    for (int l = 0; l < NLAYER; ++l) {
        n_xs<<<(T_SEQ * HN) / 256, 256, 0, stream>>>(x, dec_x, xs);
        mfma_scores<<<dim3(16, 16, NHEAD), 256, 0, stream>>>(xs, cosT, sinT, sc);
        n_ykv<<<(NHEAD * T_SEQ * D_DIM) / 256, 256, 0, stream>>>(sc, x, ykv);
        n_ln<<<(NHEAD * T_SEQ + 63) / 64, 64, 0, stream>>>(ykv, NHEAD * T_SEQ);
        n_ysp<<<(T_SEQ * HN) / 256, 256, 0, stream>>>(ykv, dec_y, xs);
        n_ymlp<<<(T_SEQ * D_DIM) / 256, 256, 0, stream>>>(xs, enc, ymlp);
        n_resid<<<(T_SEQ + 63) / 64, 64, 0, stream>>>(x, ymlp);
    }

    n_logits<<<(T_SEQ * VOCABSZ) / 256, 256, 0, stream>>>(x, lmh, out);
}

// Round 7
// 1348.366 us; speedup vs baseline: 58.8237x; 7.0447x over previous
//
#include <hip/hip_runtime.h>
#include <hip/hip_bf16.h>

using bf16 = __hip_bfloat16;

#define D_DIM   192
#define N_DIM   3072
#define NHEAD   4
#define T_SEQ   1024
#define HN      12288      // NHEAD * N_DIM
#define NP2     1536       // N_DIM/2
#define VOCABSZ 256
#define NLAYER  4
#define LN_EPS  1e-5f
#define TWO_PI  6.2831853071795864f

typedef __attribute__((ext_vector_type(8))) short          s16x8;
typedef __attribute__((ext_vector_type(8))) unsigned short u16x8;
typedef __attribute__((ext_vector_type(4))) float          f32x4;

__device__ __forceinline__ float b2f(bf16 v) { return __bfloat162float(v); }
__device__ __forceinline__ float us2f(unsigned short u) {
    unsigned int x = ((unsigned int)u) << 16;
    return __builtin_bit_cast(float, x);
}
__device__ __forceinline__ unsigned short f2us(float f) {
    bf16 b = __float2bfloat16(f);
    return __builtin_bit_cast(unsigned short, b);
}

// sentinel: encode ws_size into every output element
__global__ void fill_out(float* __restrict__ out, float val, int nelem) {
    int i = blockIdx.x * 256 + threadIdx.x;
    if (i < nelem) out[i] = val;
}

__global__ void n_zero(float* __restrict__ p, int nelem) {
    int i = blockIdx.x * 256 + threadIdx.x;
    if (i < nelem) p[i] = 0.f;
}

// x[t,:] = LN(embed[idx[t],:] + pos[t,:])   — one THREAD per row, two-pass
__global__ void n_embed(const int* __restrict__ idx, const float* __restrict__ emb,
                        const float* __restrict__ pos, float* __restrict__ x) {
    int t = blockIdx.x * 64 + threadIdx.x;
    if (t >= T_SEQ) return;
    int tok = idx[t];
    const float* e = emb + tok * D_DIM;
    const float* p = pos + t * D_DIM;
    float s = 0.f, ss = 0.f;
    for (int d = 0; d < D_DIM; d++) { float v = e[d] + p[d]; s += v; ss += v * v; }
    float m = s / D_DIM, var = ss / D_DIM - m * m;
    float r = rsqrtf(var + LN_EPS);
    for (int d = 0; d < D_DIM; d++) { float v = e[d] + p[d]; x[t * D_DIM + d] = (v - m) * r; }
}

// in-place rowwise LN (rows of 192), one thread per row
__global__ void n_ln(float* __restrict__ buf, int nrows) {
    int rI = blockIdx.x * 64 + threadIdx.x;
    if (rI >= nrows) return;
    float* row = buf + (size_t)rI * D_DIM;
    float s = 0.f, ss = 0.f;
    for (int d = 0; d < D_DIM; d++) { float v = row[d]; s += v; ss += v * v; }
    float m = s / D_DIM, var = ss / D_DIM - m * m;
    float r = rsqrtf(var + LN_EPS);
    for (int d = 0; d < D_DIM; d++) row[d] = (row[d] - m) * r;
}

// x[t,:] = LN(x[t,:] + LN(ymlp[t,:]))   — one thread per row
__global__ void n_resid(float* __restrict__ x, const float* __restrict__ ymlp) {
    int t = blockIdx.x * 64 + threadIdx.x;
    if (t >= T_SEQ) return;
    const float* ym = ymlp + t * D_DIM;
    float* xr = x + t * D_DIM;
    float s = 0.f, ss = 0.f;
    for (int d = 0; d < D_DIM; d++) { float v = ym[d]; s += v; ss += v * v; }
    float m1 = s / D_DIM, r1 = rsqrtf(ss / D_DIM - m1 * m1 + LN_EPS);
    s = 0.f; ss = 0.f;
    for (int d = 0; d < D_DIM; d++) { float v = xr[d] + (ym[d] - m1) * r1; s += v; ss += v * v; }
    float m2 = s / D_DIM, r2 = rsqrtf(ss / D_DIM - m2 * m2 + LN_EPS);
    for (int d = 0; d < D_DIM; d++) {
        float v = xr[d] + (ym[d] - m1) * r1;
        xr[d] = (v - m2) * r2;
    }
}

// RoPE cos/sin tables [t][p], p = n/2; mirrors np get_freqs via powf
__global__ void n_tables(float* __restrict__ cosT, float* __restrict__ sinT) {
    int gid = blockIdx.x * 256 + threadIdx.x;          // T*NP2
    if (gid >= T_SEQ * NP2) return;
    int t = gid / NP2, p = gid % NP2;
    float qf = (float)(2 * p);
    float f = 1.0f / powf(65536.0f, qf / 3072.0f) / (float)TWO_PI;
    float ph = fmodf((float)t * f, 1.0f) * (float)TWO_PI;
    cosT[gid] = cosf(ph);
    sinT[gid] = sinf(ph);
}

// ---------------------------------------------------------------------------
// MFMA causal scores: sc[h,t,s] = dot(rope(xs[t,h]), rope(xs[s,h])) for s<t.
// Diagonal tiles write 0 at s>=t so the downstream causal MFMA GEMM can read
// whole 64-aligned K-chunks. Strictly-upper tiles are never read -> early out.
// ---------------------------------------------------------------------------
__device__ __forceinline__ void stage_rope8(short* dst, const bf16* src,
                                            const float* cosP, const float* sinP) {
    u16x8 v = *(const u16x8*)src;
    float4 c = *(const float4*)cosP;
    float4 s = *(const float4*)sinP;
    u16x8 o;
    float e, od;
    e = us2f(v[0]); od = us2f(v[1]);
    o[0] = f2us(e * c.x - od * s.x); o[1] = f2us(od * c.x + e * s.x);
    e = us2f(v[2]); od = us2f(v[3]);
    o[2] = f2us(e * c.y - od * s.y); o[3] = f2us(od * c.y + e * s.y);
    e = us2f(v[4]); od = us2f(v[5]);
    o[4] = f2us(e * c.z - od * s.z); o[5] = f2us(od * c.z + e * s.z);
    e = us2f(v[6]); od = us2f(v[7]);
    o[6] = f2us(e * c.w - od * s.w); o[7] = f2us(od * c.w + e * s.w);
    *(u16x8*)dst = o;
}

__launch_bounds__(256)
__global__ void mfma_scores(const bf16* __restrict__ xs,
                            const float* __restrict__ cosT,
                            const float* __restrict__ sinT,
                            float* __restrict__ sc) {
    const int h  = blockIdx.z;
    const int s0 = blockIdx.x * 64, t0 = blockIdx.y * 64;
    if (s0 > t0) return;                 // strictly-upper tiles: never read

    __shared__ short As[64][40];         // [row][k], 80B row stride
    __shared__ short Bs[64][40];

    const int tid  = threadIdx.x;
    const int srow = tid >> 2;           // 0..63 staging row
    const int kq   = (tid & 3) * 8;      // 0,8,16,24 staging k-offset
    const int lane = tid & 63;
    const int w    = tid >> 6;           // wave 0..3 -> t-subtile
    const int qd   = lane >> 4;          // quad
    const int lc   = lane & 15;

    const int tA = t0 + srow, tB = s0 + srow;
    const bf16*  gA = xs   + (size_t)tA * HN + h * N_DIM + kq;
    const bf16*  gB = xs   + (size_t)tB * HN + h * N_DIM + kq;
    const float* cA = cosT + (size_t)tA * NP2 + (kq >> 1);
    const float* sA = sinT + (size_t)tA * NP2 + (kq >> 1);
    const float* cB = cosT + (size_t)tB * NP2 + (kq >> 1);
    const float* sB = sinT + (size_t)tB * NP2 + (kq >> 1);

    f32x4 acc[4] = {{0.f,0.f,0.f,0.f},{0.f,0.f,0.f,0.f},
                    {0.f,0.f,0.f,0.f},{0.f,0.f,0.f,0.f}};

    for (int k0 = 0; k0 < N_DIM; k0 += 32) {
        stage_rope8(&As[srow][kq], gA + k0, cA + (k0 >> 1), sA + (k0 >> 1));
        stage_rope8(&Bs[srow][kq], gB + k0, cB + (k0 >> 1), sB + (k0 >> 1));
        __syncthreads();
        s16x8 a = *(const s16x8*)&As[w * 16 + lc][qd * 8];
        #pragma unroll
        for (int j = 0; j < 4; j++) {
            s16x8 b = *(const s16x8*)&Bs[j * 16 + lc][qd * 8];
            acc[j] = __builtin_amdgcn_mfma_f32_16x16x32_bf16(a, b, acc[j], 0, 0, 0);
        }
        __syncthreads();
    }

    float* C = sc + (size_t)h * T_SEQ * T_SEQ;
    const bool diag = (s0 == t0);
    const int tbase = t0 + w * 16 + qd * 4;
    #pragma unroll
    for (int j = 0; j < 4; j++) {
        int s = s0 + j * 16 + lc;
        #pragma unroll
        for (int r = 0; r < 4; r++) {
            int t = tbase + r;
            C[(size_t)t * T_SEQ + s] = (!diag || s < t) ? acc[j][r] : 0.f;
        }
    }
}

// ---------------------------------------------------------------------------
// Generic MFMA GEMM: C(M x N) = A(M x K) * B(K x N), 64x64 tile per block,
// operands staged to bf16 LDS (fp32 inputs rounded), fp32 accumulate.
// Fragment layout identical to mfma_scores (hardware-validated).
// EPI: 0 = fp32 store, 1 = relu -> bf16 store, 2 = in-place bf16 gate
//      (C *= relu(acc)), 3 = fp32 atomicAdd (split-K).
// CAUSAL: K-loop upper bound = m0+64 (A = causal scores, zero-filled diag).
// SPLITK: z indexes K-segment of length kSeg instead of head.
// ---------------------------------------------------------------------------
template <typename TA, typename TC, int EPI, bool CAUSAL, bool SPLITK>
__launch_bounds__(256)
__global__ void mfma_gemm(const TA* __restrict__ A, const float* __restrict__ B,
                          TC* __restrict__ C,
                          int K, int kSeg, int lda, int ldb, int ldc,
                          long aZ, long bZ, long cZ) {
    __shared__ short As[64][40];     // [m][k]
    __shared__ short Bs[64][40];     // [n][k]  (B^T tile)

    const int z = blockIdx.z;
    A += aZ * z;  B += bZ * z;  C += cZ * z;

    const int tid  = threadIdx.x;
    const int n0 = blockIdx.x * 64, m0 = blockIdx.y * 64;

    // A staging: thread -> (row, 8-wide k chunk)
    const int sArow = tid >> 2, sAk = (tid & 3) * 8;
    // B staging: thread -> (k row, 8-wide n chunk); writes transposed
    const int sBk = tid >> 3, sBn = (tid & 7) * 8;

    const int lane = tid & 63;
    const int w    = tid >> 6;
    const int qd   = lane >> 4;
    const int lc   = lane & 15;

    int kBeg, kEnd;
    if (SPLITK) { kBeg = z * kSeg; kEnd = kBeg + kSeg; }
    else        { kBeg = 0; kEnd = CAUSAL ? (m0 + 64 < K ? m0 + 64 : K) : K; }

    f32x4 acc[4] = {{0.f,0.f,0.f,0.f},{0.f,0.f,0.f,0.f},
                    {0.f,0.f,0.f,0.f},{0.f,0.f,0.f,0.f}};

    for (int k0 = kBeg; k0 < kEnd; k0 += 32) {
        // --- stage A tile (64 rows x 32 k) ---
        {
            const TA* ga = A + (size_t)(m0 + sArow) * lda + k0 + sAk;
            u16x8 o;
            if constexpr (__is_same(TA, float)) {
                float4 f0 = *(const float4*)ga;
                float4 f1 = *(const float4*)(ga + 4);
                o[0] = f2us(f0.x); o[1] = f2us(f0.y); o[2] = f2us(f0.z); o[3] = f2us(f0.w);
                o[4] = f2us(f1.x); o[5] = f2us(f1.y); o[6] = f2us(f1.z); o[7] = f2us(f1.w);
            } else {
                o = *(const u16x8*)ga;
            }
            *(u16x8*)&As[sArow][sAk] = o;
        }
        // --- stage B tile transposed (32 k x 64 n -> Bs[n][k]) ---
        {
            const float* gb = B + (size_t)(k0 + sBk) * ldb + n0 + sBn;
            float4 f0 = *(const float4*)gb;
            float4 f1 = *(const float4*)(gb + 4);
            Bs[sBn + 0][sBk] = (short)f2us(f0.x);
            Bs[sBn + 1][sBk] = (short)f2us(f0.y);
            Bs[sBn + 2][sBk] = (short)f2us(f0.z);
            Bs[sBn + 3][sBk] = (short)f2us(f0.w);
            Bs[sBn + 4][sBk] = (short)f2us(f1.x);
            Bs[sBn + 5][sBk] = (short)f2us(f1.y);
            Bs[sBn + 6][sBk] = (short)f2us(f1.z);
            Bs[sBn + 7][sBk] = (short)f2us(f1.w);
        }
        __syncthreads();
        s16x8 a = *(const s16x8*)&As[w * 16 + lc][qd * 8];
        #pragma unroll
        for (int j = 0; j < 4; j++) {
            s16x8 b = *(const s16x8*)&Bs[j * 16 + lc][qd * 8];
            acc[j] = __builtin_amdgcn_mfma_f32_16x16x32_bf16(a, b, acc[j], 0, 0, 0);
        }
        __syncthreads();
    }

    #pragma unroll
    for (int j = 0; j < 4; j++) {
        int n = n0 + j * 16 + lc;
        #pragma unroll
        for (int r = 0; r < 4; r++) {
            int m = m0 + w * 16 + qd * 4 + r;
            float v = acc[j][r];
            size_t ci = (size_t)m * ldc + n;
            if constexpr (EPI == 0) {
                ((float*)C)[ci] = v;
            } else if constexpr (EPI == 1) {
                ((bf16*)C)[ci] = __float2bfloat16(fmaxf(v, 0.f));
            } else if constexpr (EPI == 2) {
                bf16* cp = (bf16*)C + ci;
                *cp = __float2bfloat16(b2f(*cp) * fmaxf(v, 0.f));
            } else {
                atomicAdd((float*)C + ci, v);
            }
        }
    }
}

extern "C" void kernel_launch(void* const* d_in, const int* in_sizes, int n_in,
                              void* d_out, int out_size, void* d_ws, size_t ws_size,
                              hipStream_t stream) {
    const int*   idx   = (const int*)  d_in[0];
    const float* dec_x = (const float*)d_in[1];   // (NH, D, N)
    const float* dec_y = (const float*)d_in[2];   // (NH, D, N)
    const float* enc   = (const float*)d_in[3];   // (NH*N, D)
    const float* emb   = (const float*)d_in[4];   // (VOCAB, D)
    const float* pose  = (const float*)d_in[5];   // (BLOCK, D)
    const float* lmh   = (const float*)d_in[6];   // (D, VOCAB)
    float* out = (float*)d_out;                   // (T, VOCAB) fp32

    // workspace layout — 59,244,544 bytes (identical to passing r5/r6)
    float* x    = (float*)d_ws;                               //   786,432
    bf16*  xs   = (bf16*)(x + (size_t)T_SEQ * D_DIM);         //25,165,824 (x_sparse / xy)
    float* cosT = (float*)(xs + (size_t)T_SEQ * HN);          // 6,291,456
    float* sinT = cosT + (size_t)T_SEQ * NP2;                 // 6,291,456
    float* sc   = sinT + (size_t)T_SEQ * NP2;                 //16,777,216
    float* ykv  = sc + (size_t)NHEAD * T_SEQ * T_SEQ;         // 3,145,728
    float* ymlp = ykv + (size_t)NHEAD * T_SEQ * D_DIM;        //   786,432
    const size_t NEED = (size_t)(ymlp + T_SEQ * D_DIM - (float*)d_ws) * 4;

    if (ws_size < NEED) {
        fill_out<<<(out_size + 255) / 256, 256, 0, stream>>>(out, (float)ws_size, out_size);
        return;
    }

    n_embed<<<(T_SEQ + 63) / 64, 64, 0, stream>>>(idx, emb, pose, x);
    n_tables<<<(T_SEQ * NP2 + 255) / 256, 256, 0, stream>>>(cosT, sinT);

    for (int l = 0; l < NLAYER; ++l) {
        // xs = relu(x @ dec_x[h])                  M=1024 N=3072 K=192, bf16 out
        mfma_gemm<float, bf16, 1, false, false><<<dim3(48, 16, NHEAD), 256, 0, stream>>>(
            x, dec_x, xs, D_DIM, 0, D_DIM, N_DIM, HN,
            0L, (long)D_DIM * N_DIM, (long)N_DIM);
        // scores = tril(rope(xs) rope(xs)^T, -1)
        mfma_scores<<<dim3(16, 16, NHEAD), 256, 0, stream>>>(xs, cosT, sinT, sc);
        // ykv = sc @ x                             M=1024 N=192 K=1024 causal
        mfma_gemm<float, float, 0, true, false><<<dim3(3, 16, NHEAD), 256, 0, stream>>>(
            sc, x, ykv, T_SEQ, 0, T_SEQ, D_DIM, D_DIM,
            (long)T_SEQ * T_SEQ, 0L, (long)T_SEQ * D_DIM);
        // ykv = LN(ykv) rowwise
        n_ln<<<(NHEAD * T_SEQ + 63) / 64, 64, 0, stream>>>(ykv, NHEAD * T_SEQ);
        // xs *= relu(ykv @ dec_y[h])  (gate, in place)
        mfma_gemm<float, bf16, 2, false, false><<<dim3(48, 16, NHEAD), 256, 0, stream>>>(
            ykv, dec_y, xs, D_DIM, 0, D_DIM, N_DIM, HN,
            (long)T_SEQ * D_DIM, (long)D_DIM * N_DIM, (long)N_DIM);
        // ymlp = xy @ enc                          M=1024 N=192 K=12288, split-K=8
        n_zero<<<(T_SEQ * D_DIM + 255) / 256, 256, 0, stream>>>(ymlp, T_SEQ * D_DIM);
        mfma_gemm<bf16, float, 3, false, true><<<dim3(3, 16, 8), 256, 0, stream>>>(
            xs, enc, ymlp, HN, HN / 8, HN, D_DIM, D_DIM,
            0L, 0L, 0L);
        // x = LN(x + LN(ymlp))
        n_resid<<<(T_SEQ + 63) / 64, 64, 0, stream>>>(x, ymlp);
    }

    // logits = x @ lm_head                         M=1024 N=256 K=192
    mfma_gemm<float, float, 0, false, false><<<dim3(4, 16, 1), 256, 0, stream>>>(
        x, lmh, out, D_DIM, 0, D_DIM, VOCABSZ, VOCABSZ, 0L, 0L, 0L);
}

// Round 8
// 804.666 us; speedup vs baseline: 98.5699x; 1.6757x over previous
//
#include <hip/hip_runtime.h>
#include <hip/hip_bf16.h>

using bf16 = __hip_bfloat16;

#define D_DIM   192
#define N_DIM   3072
#define NHEAD   4
#define T_SEQ   1024
#define HN      12288      // NHEAD * N_DIM
#define NP2     1536       // N_DIM/2
#define VOCABSZ 256
#define NLAYER  4
#define LN_EPS  1e-5f
#define TWO_PI  6.2831853071795864f

typedef __attribute__((ext_vector_type(8))) short          s16x8;
typedef __attribute__((ext_vector_type(8))) unsigned short u16x8;
typedef __attribute__((ext_vector_type(4))) float          f32x4;

__device__ __forceinline__ float b2f(bf16 v) { return __bfloat162float(v); }
__device__ __forceinline__ float us2f(unsigned short u) {
    unsigned int x = ((unsigned int)u) << 16;
    return __builtin_bit_cast(float, x);
}
__device__ __forceinline__ unsigned short f2us(float f) {
    bf16 b = __float2bfloat16(f);
    return __builtin_bit_cast(unsigned short, b);
}

// sentinel: encode ws_size into every output element (fires only if ws too small)
__global__ void fill_out(float* __restrict__ out, float val, int nelem) {
    int i = blockIdx.x * 256 + threadIdx.x;
    if (i < nelem) out[i] = val;
}

__global__ void n_zero(float* __restrict__ p, int nelem) {
    int i = blockIdx.x * 256 + threadIdx.x;
    if (i < nelem) p[i] = 0.f;
}

// ---------------------------------------------------------------------------
// Tiled transpose + fp32->bf16 convert: in fp32 [R][C] -> out bf16 [C][R].
// grid (C/64, R/64, Z). 64x64 tile via LDS.
// ---------------------------------------------------------------------------
__global__ void t_cvt(const float* __restrict__ in, bf16* __restrict__ out,
                      int R, int C, long inZ, long outZ) {
    __shared__ float tile[64][65];
    in  += inZ  * blockIdx.z;
    out += outZ * blockIdx.z;
    const int tx = threadIdx.x & 63, ty = threadIdx.x >> 6;   // ty 0..3
    const int r0 = blockIdx.y * 64, c0 = blockIdx.x * 64;
    #pragma unroll
    for (int rr = 0; rr < 16; rr++) {
        int row = ty * 16 + rr;
        tile[row][tx] = in[(size_t)(r0 + row) * C + c0 + tx];
    }
    __syncthreads();
    #pragma unroll
    for (int rr = 0; rr < 16; rr++) {
        int row = ty * 16 + rr;   // output row = column index
        out[(size_t)(c0 + row) * R + r0 + tx] = __float2bfloat16(tile[tx][row]);
    }
}

// ---------------------------------------------------------------------------
// Wave-per-row LN family (64 threads/block, 3 elems/lane, butterfly reduce)
// ---------------------------------------------------------------------------
__device__ __forceinline__ void wave_sum2(float& s, float& ss) {
    #pragma unroll
    for (int off = 1; off < 64; off <<= 1) {
        s  += __shfl_xor(s,  off, 64);
        ss += __shfl_xor(ss, off, 64);
    }
}

__global__ void k_embed(const int* __restrict__ idx, const float* __restrict__ emb,
                        const float* __restrict__ pos, float* __restrict__ x) {
    int t = blockIdx.x, l = threadIdx.x;
    int tok = idx[t];
    const float* e = emb + tok * D_DIM;
    const float* p = pos + t * D_DIM;
    float v0 = e[l] + p[l], v1 = e[l + 64] + p[l + 64], v2 = e[l + 128] + p[l + 128];
    float s = v0 + v1 + v2, ss = v0 * v0 + v1 * v1 + v2 * v2;
    wave_sum2(s, ss);
    float m = s / D_DIM, r = rsqrtf(ss / D_DIM - m * m + LN_EPS);
    float* xr = x + t * D_DIM;
    xr[l] = (v0 - m) * r; xr[l + 64] = (v1 - m) * r; xr[l + 128] = (v2 - m) * r;
}

__global__ void k_ln(float* __restrict__ buf) {
    int l = threadIdx.x;
    float* row = buf + (size_t)blockIdx.x * D_DIM;
    float v0 = row[l], v1 = row[l + 64], v2 = row[l + 128];
    float s = v0 + v1 + v2, ss = v0 * v0 + v1 * v1 + v2 * v2;
    wave_sum2(s, ss);
    float m = s / D_DIM, r = rsqrtf(ss / D_DIM - m * m + LN_EPS);
    row[l] = (v0 - m) * r; row[l + 64] = (v1 - m) * r; row[l + 128] = (v2 - m) * r;
}

__global__ void k_resid(float* __restrict__ x, const float* __restrict__ ymlp) {
    int l = threadIdx.x;
    const float* ym = ymlp + (size_t)blockIdx.x * D_DIM;
    float* xr = x + (size_t)blockIdx.x * D_DIM;
    float y0 = ym[l], y1 = ym[l + 64], y2 = ym[l + 128];
    float s = y0 + y1 + y2, ss = y0 * y0 + y1 * y1 + y2 * y2;
    wave_sum2(s, ss);
    float m1 = s / D_DIM, r1 = rsqrtf(ss / D_DIM - m1 * m1 + LN_EPS);
    float v0 = xr[l] + (y0 - m1) * r1;
    float v1 = xr[l + 64] + (y1 - m1) * r1;
    float v2 = xr[l + 128] + (y2 - m1) * r1;
    s = v0 + v1 + v2; ss = v0 * v0 + v1 * v1 + v2 * v2;
    wave_sum2(s, ss);
    float m2 = s / D_DIM, r2 = rsqrtf(ss / D_DIM - m2 * m2 + LN_EPS);
    xr[l] = (v0 - m2) * r2; xr[l + 64] = (v1 - m2) * r2; xr[l + 128] = (v2 - m2) * r2;
}

// RoPE cos/sin tables as interleaved bf16 pairs csT[t][p] = (cos, sin)
__global__ void k_tables(ushort2* __restrict__ csT) {
    int gid = blockIdx.x * 256 + threadIdx.x;          // T*NP2
    int t = gid / NP2, p = gid % NP2;
    float qf = (float)(2 * p);
    float f = 1.0f / powf(65536.0f, qf / 3072.0f) / (float)TWO_PI;
    float ph = fmodf((float)t * f, 1.0f) * (float)TWO_PI;
    ushort2 cs;
    cs.x = f2us(cosf(ph));
    cs.y = f2us(sinf(ph));
    csT[gid] = cs;
}

// qr = rope(xs), vectorized 8 elems (4 pairs) per thread
__global__ void k_rope(const bf16* __restrict__ xs, const ushort2* __restrict__ csT,
                       bf16* __restrict__ qr) {
    int gid = blockIdx.x * 256 + threadIdx.x;          // T*HN/8
    int e8 = gid * 8;
    int t = e8 / HN;
    int n = (e8 % HN) % N_DIM;                         // within-head dim
    int p = n >> 1;
    u16x8 v  = *(const u16x8*)(xs + e8);
    u16x8 cs = *(const u16x8*)(csT + (size_t)t * NP2 + p);
    u16x8 o;
    #pragma unroll
    for (int i = 0; i < 4; i++) {
        float e  = us2f(v[2 * i]), od = us2f(v[2 * i + 1]);
        float c  = us2f(cs[2 * i]), s = us2f(cs[2 * i + 1]);
        o[2 * i]     = f2us(e * c - od * s);
        o[2 * i + 1] = f2us(od * c + e * s);
    }
    *(u16x8*)(qr + e8) = o;
}

// ---------------------------------------------------------------------------
// scores (qr path): pure bf16 GEMM  sc[h,t,s] = dot(qr[t,h], qr[s,h]), causal.
// 64x64 tile; staging = u16x8 copies; diag masks s>=t to 0; upper tiles skip.
// ---------------------------------------------------------------------------
__launch_bounds__(256)
__global__ void scores_qr(const bf16* __restrict__ qr, bf16* __restrict__ sc) {
    const int h  = blockIdx.z;
    const int s0 = blockIdx.x * 64, t0 = blockIdx.y * 64;
    if (s0 > t0) return;

    __shared__ short As[64][40];
    __shared__ short Bs[64][40];

    const int tid  = threadIdx.x;
    const int srow = tid >> 2, kq = (tid & 3) * 8;
    const int lane = tid & 63, w = tid >> 6, qd = lane >> 4, lc = lane & 15;

    const bf16* gA = qr + (size_t)(t0 + srow) * HN + h * N_DIM + kq;
    const bf16* gB = qr + (size_t)(s0 + srow) * HN + h * N_DIM + kq;

    f32x4 acc[4] = {{0.f,0.f,0.f,0.f},{0.f,0.f,0.f,0.f},
                    {0.f,0.f,0.f,0.f},{0.f,0.f,0.f,0.f}};

    for (int k0 = 0; k0 < N_DIM; k0 += 32) {
        *(u16x8*)&As[srow][kq] = *(const u16x8*)(gA + k0);
        *(u16x8*)&Bs[srow][kq] = *(const u16x8*)(gB + k0);
        __syncthreads();
        s16x8 a = *(const s16x8*)&As[w * 16 + lc][qd * 8];
        #pragma unroll
        for (int j = 0; j < 4; j++) {
            s16x8 b = *(const s16x8*)&Bs[j * 16 + lc][qd * 8];
            acc[j] = __builtin_amdgcn_mfma_f32_16x16x32_bf16(a, b, acc[j], 0, 0, 0);
        }
        __syncthreads();
    }

    bf16* C = sc + (size_t)h * T_SEQ * T_SEQ;
    const bool diag = (s0 == t0);
    const int tbase = t0 + w * 16 + qd * 4;
    #pragma unroll
    for (int j = 0; j < 4; j++) {
        int s = s0 + j * 16 + lc;
        #pragma unroll
        for (int r = 0; r < 4; r++) {
            int t = tbase + r;
            C[(size_t)t * T_SEQ + s] =
                __float2bfloat16((!diag || s < t) ? acc[j][r] : 0.f);
        }
    }
}

// ---------------------------------------------------------------------------
// scores fallback (no qr buffer): rope fused into staging, bf16 tables/out.
// ---------------------------------------------------------------------------
__device__ __forceinline__ void stage_rope8(short* dst, const bf16* src,
                                            const ushort2* csP) {
    u16x8 v  = *(const u16x8*)src;
    u16x8 cs = *(const u16x8*)csP;
    u16x8 o;
    #pragma unroll
    for (int i = 0; i < 4; i++) {
        float e  = us2f(v[2 * i]), od = us2f(v[2 * i + 1]);
        float c  = us2f(cs[2 * i]), s = us2f(cs[2 * i + 1]);
        o[2 * i]     = f2us(e * c - od * s);
        o[2 * i + 1] = f2us(od * c + e * s);
    }
    *(u16x8*)dst = o;
}

__launch_bounds__(256)
__global__ void scores_fused(const bf16* __restrict__ xs,
                             const ushort2* __restrict__ csT,
                             bf16* __restrict__ sc) {
    const int h  = blockIdx.z;
    const int s0 = blockIdx.x * 64, t0 = blockIdx.y * 64;
    if (s0 > t0) return;

    __shared__ short As[64][40];
    __shared__ short Bs[64][40];

    const int tid  = threadIdx.x;
    const int srow = tid >> 2, kq = (tid & 3) * 8;
    const int lane = tid & 63, w = tid >> 6, qd = lane >> 4, lc = lane & 15;

    const int tA = t0 + srow, tB = s0 + srow;
    const bf16* gA = xs + (size_t)tA * HN + h * N_DIM + kq;
    const bf16* gB = xs + (size_t)tB * HN + h * N_DIM + kq;
    const ushort2* cA = csT + (size_t)tA * NP2 + (kq >> 1);
    const ushort2* cB = csT + (size_t)tB * NP2 + (kq >> 1);

    f32x4 acc[4] = {{0.f,0.f,0.f,0.f},{0.f,0.f,0.f,0.f},
                    {0.f,0.f,0.f,0.f},{0.f,0.f,0.f,0.f}};

    for (int k0 = 0; k0 < N_DIM; k0 += 32) {
        stage_rope8(&As[srow][kq], gA + k0, cA + (k0 >> 1));
        stage_rope8(&Bs[srow][kq], gB + k0, cB + (k0 >> 1));
        __syncthreads();
        s16x8 a = *(const s16x8*)&As[w * 16 + lc][qd * 8];
        #pragma unroll
        for (int j = 0; j < 4; j++) {
            s16x8 b = *(const s16x8*)&Bs[j * 16 + lc][qd * 8];
            acc[j] = __builtin_amdgcn_mfma_f32_16x16x32_bf16(a, b, acc[j], 0, 0, 0);
        }
        __syncthreads();
    }

    bf16* C = sc + (size_t)h * T_SEQ * T_SEQ;
    const bool diag = (s0 == t0);
    const int tbase = t0 + w * 16 + qd * 4;
    #pragma unroll
    for (int j = 0; j < 4; j++) {
        int s = s0 + j * 16 + lc;
        #pragma unroll
        for (int r = 0; r < 4; r++) {
            int t = tbase + r;
            C[(size_t)t * T_SEQ + s] =
                __float2bfloat16((!diag || s < t) ? acc[j][r] : 0.f);
        }
    }
}

// ---------------------------------------------------------------------------
// MFMA GEMM v2: C(MxN) = A(MxK) * Bt^T where Bt is bf16 [n][k] (pre-transposed).
// A: fp32 (cvt at staging) or bf16. 64x64 tile, BK=32, fp32 accumulate.
// EPI: 0 fp32 store, 1 relu->bf16, 2 in-place bf16 gate, 3 fp32 atomicAdd.
// CAUSAL: kEnd = min(m0+64, K).  SPLITK: z = K segment (length kSeg).
// ---------------------------------------------------------------------------
template <typename TA, typename TC, int EPI, bool CAUSAL, bool SPLITK>
__launch_bounds__(256)
__global__ void mfma_gemm(const TA* __restrict__ A, const bf16* __restrict__ Bt,
                          TC* __restrict__ C,
                          int K, int kSeg, int lda, int ldb, int ldc,
                          long aZ, long bZ, long cZ) {
    __shared__ short As[64][40];     // [m][k]
    __shared__ short Bs[64][40];     // [n][k]

    const int z = blockIdx.z;
    A += aZ * z;  Bt += bZ * z;  C += cZ * z;

    const int tid = threadIdx.x;
    const int n0 = blockIdx.x * 64, m0 = blockIdx.y * 64;
    const int srow = tid >> 2, sk = (tid & 3) * 8;
    const int lane = tid & 63, w = tid >> 6, qd = lane >> 4, lc = lane & 15;

    int kBeg, kEnd;
    if (SPLITK) { kBeg = z * kSeg; kEnd = kBeg + kSeg; }
    else        { kBeg = 0; kEnd = CAUSAL ? (m0 + 64 < K ? m0 + 64 : K) : K; }

    const TA*   ga = A  + (size_t)(m0 + srow) * lda + sk;
    const bf16* gb = Bt + (size_t)(n0 + srow) * ldb + sk;

    f32x4 acc[4] = {{0.f,0.f,0.f,0.f},{0.f,0.f,0.f,0.f},
                    {0.f,0.f,0.f,0.f},{0.f,0.f,0.f,0.f}};

    for (int k0 = kBeg; k0 < kEnd; k0 += 32) {
        if constexpr (__is_same(TA, float)) {
            float4 f0 = *(const float4*)(ga + k0);
            float4 f1 = *(const float4*)(ga + k0 + 4);
            u16x8 o;
            o[0] = f2us(f0.x); o[1] = f2us(f0.y); o[2] = f2us(f0.z); o[3] = f2us(f0.w);
            o[4] = f2us(f1.x); o[5] = f2us(f1.y); o[6] = f2us(f1.z); o[7] = f2us(f1.w);
            *(u16x8*)&As[srow][sk] = o;
        } else {
            *(u16x8*)&As[srow][sk] = *(const u16x8*)(ga + k0);
        }
        *(u16x8*)&Bs[srow][sk] = *(const u16x8*)(gb + k0);
        __syncthreads();
        s16x8 a = *(const s16x8*)&As[w * 16 + lc][qd * 8];
        #pragma unroll
        for (int j = 0; j < 4; j++) {
            s16x8 b = *(const s16x8*)&Bs[j * 16 + lc][qd * 8];
            acc[j] = __builtin_amdgcn_mfma_f32_16x16x32_bf16(a, b, acc[j], 0, 0, 0);
        }
        __syncthreads();
    }

    #pragma unroll
    for (int j = 0; j < 4; j++) {
        int n = n0 + j * 16 + lc;
        #pragma unroll
        for (int r = 0; r < 4; r++) {
            int m = m0 + w * 16 + qd * 4 + r;
            float v = acc[j][r];
            size_t ci = (size_t)m * ldc + n;
            if constexpr (EPI == 0) {
                ((float*)C)[ci] = v;
            } else if constexpr (EPI == 1) {
                ((bf16*)C)[ci] = __float2bfloat16(fmaxf(v, 0.f));
            } else if constexpr (EPI == 2) {
                bf16* cp = (bf16*)C + ci;
                *cp = __float2bfloat16(b2f(*cp) * fmaxf(v, 0.f));
            } else {
                atomicAdd((float*)C + ci, v);
            }
        }
    }
}

extern "C" void kernel_launch(void* const* d_in, const int* in_sizes, int n_in,
                              void* d_out, int out_size, void* d_ws, size_t ws_size,
                              hipStream_t stream) {
    const int*   idx   = (const int*)  d_in[0];
    const float* dec_x = (const float*)d_in[1];   // (NH, D, N)
    const float* dec_y = (const float*)d_in[2];   // (NH, D, N)
    const float* enc   = (const float*)d_in[3];   // (NH*N, D)
    const float* emb   = (const float*)d_in[4];   // (VOCAB, D)
    const float* pose  = (const float*)d_in[5];   // (BLOCK, D)
    const float* lmh   = (const float*)d_in[6];   // (D, VOCAB)
    float* out = (float*)d_out;                   // (T, VOCAB) fp32

    // base workspace: 59,211,776 B  (proven ws_size >= 59,244,544)
    char* wp = (char*)d_ws;
    float*   x    = (float*)wp;              wp += (size_t)T_SEQ * D_DIM * 4;      //   786,432
    bf16*    xs   = (bf16*)wp;               wp += (size_t)T_SEQ * HN * 2;         //25,165,824
    ushort2* csT  = (ushort2*)wp;            wp += (size_t)T_SEQ * NP2 * 4;        // 6,291,456
    bf16*    sc   = (bf16*)wp;               wp += (size_t)NHEAD * T_SEQ * T_SEQ * 2; // 8,388,608
    float*   ykv  = (float*)wp;              wp += (size_t)NHEAD * T_SEQ * D_DIM * 4; // 3,145,728
    float*   ymlp = (float*)wp;              wp += (size_t)T_SEQ * D_DIM * 4;      //   786,432
    bf16*    xT   = (bf16*)wp;               wp += (size_t)D_DIM * T_SEQ * 2;      //   393,216
    bf16*    wX   = (bf16*)wp;               wp += (size_t)NHEAD * N_DIM * D_DIM * 2; // 4,718,592
    bf16*    wY   = (bf16*)wp;               wp += (size_t)NHEAD * N_DIM * D_DIM * 2; // 4,718,592
    bf16*    wE   = (bf16*)wp;               wp += (size_t)D_DIM * HN * 2;         // 4,718,592
    bf16*    wL   = (bf16*)wp;               wp += (size_t)VOCABSZ * D_DIM * 2;    //    98,304
    const size_t BASE_NEED = (size_t)(wp - (char*)d_ws);
    bf16*    qr   = (bf16*)wp;               // +25,165,824 if available
    const size_t FULL_NEED = BASE_NEED + (size_t)T_SEQ * HN * 2;

    if (ws_size < BASE_NEED) {
        fill_out<<<(out_size + 255) / 256, 256, 0, stream>>>(out, (float)ws_size, out_size);
        return;
    }
    const bool USE_QR = (ws_size >= FULL_NEED);

    // weight mirrors (bf16, [n][k])
    t_cvt<<<dim3(48, 3, 4), 256, 0, stream>>>(dec_x, wX, D_DIM, N_DIM,
                                              (long)D_DIM * N_DIM, (long)N_DIM * D_DIM);
    t_cvt<<<dim3(48, 3, 4), 256, 0, stream>>>(dec_y, wY, D_DIM, N_DIM,
                                              (long)D_DIM * N_DIM, (long)N_DIM * D_DIM);
    t_cvt<<<dim3(3, 192, 1), 256, 0, stream>>>(enc, wE, HN, D_DIM, 0L, 0L);
    t_cvt<<<dim3(4, 3, 1), 256, 0, stream>>>(lmh, wL, D_DIM, VOCABSZ, 0L, 0L);

    k_tables<<<(T_SEQ * NP2) / 256, 256, 0, stream>>>(csT);
    k_embed<<<T_SEQ, 64, 0, stream>>>(idx, emb, pose, x);

    for (int l = 0; l < NLAYER; ++l) {
        // xT = x^T (bf16), for ykv GEMM's B operand
        t_cvt<<<dim3(3, 16, 1), 256, 0, stream>>>(x, xT, T_SEQ, D_DIM, 0L, 0L);
        // xs = relu(x @ dec_x[h])
        mfma_gemm<float, bf16, 1, false, false><<<dim3(48, 16, NHEAD), 256, 0, stream>>>(
            x, wX, xs, D_DIM, 0, D_DIM, D_DIM, HN,
            0L, (long)N_DIM * D_DIM, (long)N_DIM);
        // scores
        if (USE_QR) {
            k_rope<<<(T_SEQ * HN / 8) / 256, 256, 0, stream>>>(xs, csT, qr);
            scores_qr<<<dim3(16, 16, NHEAD), 256, 0, stream>>>(qr, sc);
        } else {
            scores_fused<<<dim3(16, 16, NHEAD), 256, 0, stream>>>(xs, csT, sc);
        }
        // ykv = sc @ x   (causal K)
        mfma_gemm<bf16, float, 0, true, false><<<dim3(3, 16, NHEAD), 256, 0, stream>>>(
            sc, xT, ykv, T_SEQ, 0, T_SEQ, T_SEQ, D_DIM,
            (long)T_SEQ * T_SEQ, 0L, (long)T_SEQ * D_DIM);
        // ykv = LN(ykv)
        k_ln<<<NHEAD * T_SEQ, 64, 0, stream>>>(ykv);
        // xs *= relu(ykv @ dec_y[h])   (gate)
        mfma_gemm<float, bf16, 2, false, false><<<dim3(48, 16, NHEAD), 256, 0, stream>>>(
            ykv, wY, xs, D_DIM, 0, D_DIM, D_DIM, HN,
            (long)T_SEQ * D_DIM, (long)N_DIM * D_DIM, (long)N_DIM);
        // ymlp = xy @ enc   (split-K=8, atomic)
        n_zero<<<(T_SEQ * D_DIM + 255) / 256, 256, 0, stream>>>(ymlp, T_SEQ * D_DIM);
        mfma_gemm<bf16, float, 3, false, true><<<dim3(3, 16, 8), 256, 0, stream>>>(
            xs, wE, ymlp, HN, HN / 8, HN, HN, D_DIM, 0L, 0L, 0L);
        // x = LN(x + LN(ymlp))
        k_resid<<<T_SEQ, 64, 0, stream>>>(x, ymlp);
    }

    // logits = x @ lm_head
    mfma_gemm<float, float, 0, false, false><<<dim3(4, 16, 1), 256, 0, stream>>>(
        x, wL, out, D_DIM, 0, D_DIM, D_DIM, VOCABSZ, 0L, 0L, 0L);
}